// Round 1
// baseline (158.780 us; speedup 1.0000x reference)
//
#include <hip/hip_runtime.h>

// PercolationQ: per-patch occupancy fraction -> threshold -> mean over patches.
// x4:  [3,64,4096, 4, 4]  row (c,b) = 4096*16  = 65536 floats
// x8:  [3,64,1024, 8, 8]  row (c,b) = 1024*64  = 65536 floats
// x16: [3,64, 256,16,16]  row (c,b) =  256*256 = 65536 floats
// All rows are 65536 floats -> identical block->row mapping for all inputs.
// out: 576 floats = [q4(192) | q8(192) | q16(192)], row-major [c*64+b].

#define PERC_THRESHOLD 0.59275f

template <int B>
__device__ __forceinline__ void perc_body(const float* __restrict__ x,
                                          float* __restrict__ out,
                                          float invP) {
    constexpr int LPP = (B * B) / 4;  // lanes per patch (float4 per lane): 4 / 16 / 64
    constexpr int ITERS = 8;          // float4 loads per thread
    const int tid = threadIdx.x;
    const int lane = tid & 63;
    const float4* __restrict__ xv = (const float4*)x;
    const long long base = (long long)blockIdx.x * (256 * ITERS);
    const float thr = PERC_THRESHOLD * (float)(B * B);

    int cnt = 0;
#pragma unroll
    for (int j = 0; j < ITERS; ++j) {
        // wave reads 256 contiguous floats -> patches never straddle a wave chunk
        float4 v = xv[base + (long long)j * 256 + tid];
        float s = (v.x + v.y) + (v.z + v.w);
        // segmented butterfly sum across the LPP lanes of this patch
#pragma unroll
        for (int off = 1; off < LPP; off <<= 1)
            s += __shfl_xor(s, off, 64);
        if ((lane & (LPP - 1)) == 0 && s >= thr) cnt++;
    }

    // wave reduction of per-thread counts
#pragma unroll
    for (int off = 32; off > 0; off >>= 1)
        cnt += __shfl_down(cnt, off, 64);

    __shared__ int wsum[4];
    if (lane == 0) wsum[tid >> 6] = cnt;
    __syncthreads();
    if (tid == 0) {
        float total = (float)(wsum[0] + wsum[1] + wsum[2] + wsum[3]);
        // block covers 8192 floats; row = 65536 floats -> 8 blocks per row
        atomicAdd(&out[blockIdx.x >> 3], total * invP);  // invP is 2^-k -> exact
    }
}

__global__ __launch_bounds__(256)
void PercolationQ_31885837205970_kernel(const float* __restrict__ x4,
                                        const float* __restrict__ x8,
                                        const float* __restrict__ x16,
                                        float* __restrict__ out) {
    if (blockIdx.y == 0)      perc_body<4>(x4,  out,        1.0f / 4096.0f);
    else if (blockIdx.y == 1) perc_body<8>(x8,  out + 192,  1.0f / 1024.0f);
    else                      perc_body<16>(x16, out + 384, 1.0f / 256.0f);
}

extern "C" void kernel_launch(void* const* d_in, const int* in_sizes, int n_in,
                              void* d_out, int out_size, void* d_ws, size_t ws_size,
                              hipStream_t stream) {
    const float* x4  = (const float*)d_in[0];
    const float* x8  = (const float*)d_in[1];
    const float* x16 = (const float*)d_in[2];
    float* out = (float*)d_out;

    // d_out is re-poisoned to 0xAA before every launch; we accumulate via atomics.
    hipMemsetAsync(d_out, 0, (size_t)out_size * sizeof(float), stream);

    // per input: 12,582,912 floats = 3,145,728 float4; 2048 float4 per block -> 1536 blocks
    dim3 grid(1536, 3), block(256);
    hipLaunchKernelGGL(PercolationQ_31885837205970_kernel, grid, block, 0, stream,
                       x4, x8, x16, out);
}